// Round 17
// baseline (901.227 us; speedup 1.0000x reference)
//
#include <hip/hip_runtime.h>
#include <math.h>

#define BB 2
#define VV 4
#define NPTSC 65536
#define HH 256
#define WW 256
#define CCH 128

typedef __attribute__((ext_vector_type(8))) unsigned short ushort8;
typedef __attribute__((ext_vector_type(8))) __bf16 bf16x8;
typedef __attribute__((ext_vector_type(4))) float floatx4;

// Static buffers (independent of ws_size):
__device__ unsigned short g_feats[(size_t)BB * VV * HH * WW * CCH]; // 128 MiB
__device__ floatx4 g_rbuf[(size_t)BB * VV * 2048 * 16 * 64];        // 268 MiB
                      // layout: [bv*2048+g][frag(16)][lane(64)] float4

__device__ __forceinline__ float b2f(unsigned short u) {
  unsigned int x = ((unsigned int)u) << 16;
  return __builtin_bit_cast(float, x);
}
__device__ __forceinline__ unsigned short f2b(float f) {
  unsigned int x = __builtin_bit_cast(unsigned int, f);
  x = x + 0x7fffu + ((x >> 16) & 1u);
  return (unsigned short)(x >> 16);
}

// ---- prep: f32 weights -> bf16 [out][in] into d_ws (434 KB) ----------------
__global__ __launch_bounds__(256) void mvct_prep(
    const float* __restrict__ vw_in, const float* __restrict__ vw1,
    const float* __restrict__ vw2, const float* __restrict__ vw_out,
    const float* __restrict__ gw_in, const float* __restrict__ gw1,
    const float* __restrict__ gw2, unsigned short* __restrict__ wbuf)
{
  int tid = blockIdx.x * 256 + threadIdx.x;
  if (tid >= 217088) return;
  float val;
  if (tid < 20480) {
    int n = tid / 160, k = tid - n * 160;
    val = (k < 137) ? vw_in[k * 128 + n] : 0.f;
  } else {
    int t = tid - 20480;
    const float* src;
    if (t < 49152) { src = vw1; }
    else if (t < 98304) { t -= 49152; src = vw2; }
    else if (t < 114688) { t -= 98304; src = vw_out; }
    else if (t < 131072) { t -= 114688; src = gw_in; }
    else if (t < 163840) { t -= 131072; src = gw1; }
    else { t -= 163840; src = gw2; }
    int i = t >> 14; int r = t & 16383; int n = r >> 7; int k = r & 127;
    val = src[i * 16384 + k * 128 + n];
  }
  wbuf[tid] = f2b(val);
}

// ---- conv 3x3 SAME, 1->128 ch, relu, channel-last bf16 into g_feats --------
__global__ __launch_bounds__(128) void mvct_conv(
    const float* __restrict__ views, const float* __restrict__ conv_w,
    const float* __restrict__ conv_b)
{
  int bv = blockIdx.x >> 8;
  int y = blockIdx.x & 255;
  int c = threadIdx.x;
  float w[9];
#pragma unroll
  for (int j = 0; j < 9; ++j) w[j] = conv_w[c * 9 + j];
  float bias = conv_b[c];

  __shared__ float rows[3][258];
  const float* img = views + (size_t)bv * HH * WW;
#pragma unroll
  for (int r = 0; r < 3; ++r) {
    int yy = y - 1 + r;
    for (int x = c; x < 258; x += 128) {
      int xx = x - 1;
      float v = 0.f;
      if (yy >= 0 && yy < HH && xx >= 0 && xx < WW) v = img[yy * WW + xx];
      rows[r][x] = v;
    }
  }
  __syncthreads();

  unsigned short* orow = g_feats + ((size_t)(bv * HH + y) * WW) * CCH + c;
  for (int x = 0; x < WW; ++x) {
    float acc = bias;
#pragma unroll
    for (int r = 0; r < 3; ++r)
#pragma unroll
      for (int d = 0; d < 3; ++d)
        acc += rows[r][x + d] * w[r * 3 + d];
    acc = fmaxf(acc, 0.f);
    orow[(size_t)x * CCH] = f2b(acc);
  }
}

// ---- MFMA MLP layer; A from LDS bf16, Wt bf16 [128][K] --------------------
// Layouts (m89/m120): A[m=lane&15][k=quad*8+j]; B[n=lane&15][k=quad*8+j];
// C/D: col=lane&15, row=quad*4+reg.
// MODE 0: relu+LDS; MODE 1: relu+res+LDS; MODE 2: acc into racc;
// MODE 3: raw (bias only) -> global float4 fragment layout.
template<int K, int MODE>
__device__ __forceinline__ void mlp_layer(
    const unsigned short* A, int lda,
    const unsigned short* __restrict__ Wt,
    const float* __restrict__ bias,
    const unsigned short* Res, int ldr,
    unsigned short* Dst, int ldd,
    float* racc, floatx4* __restrict__ gout, int lane)
{
  constexpr int NK = K / 32;
  const int col = lane & 15, quad = lane >> 4;
  ushort8 a[2][NK];
#pragma unroll
  for (int mt = 0; mt < 2; ++mt)
#pragma unroll
    for (int kk = 0; kk < NK; ++kk)
      a[mt][kk] = *(const ushort8*)(A + (mt * 16 + col) * lda + kk * 32 + quad * 8);
#pragma unroll
  for (int nt = 0; nt < 8; ++nt) {
    const int n = nt * 16 + col;
    ushort8 bfr[NK];
#pragma unroll
    for (int kk = 0; kk < NK; ++kk)
      bfr[kk] = *(const ushort8*)(Wt + n * K + kk * 32 + quad * 8);
    float bsc = bias[n];
#pragma unroll
    for (int mt = 0; mt < 2; ++mt) {
      floatx4 acc = {0.f, 0.f, 0.f, 0.f};
#pragma unroll
      for (int kk = 0; kk < NK; ++kk)
        acc = __builtin_amdgcn_mfma_f32_16x16x32_bf16(
            __builtin_bit_cast(bf16x8, a[mt][kk]),
            __builtin_bit_cast(bf16x8, bfr[kk]), acc, 0, 0, 0);
      if constexpr (MODE == 3) {
        floatx4 o = {acc[0] + bsc, acc[1] + bsc, acc[2] + bsc, acc[3] + bsc};
        gout[(mt * 8 + nt) * 64 + lane] = o;
      } else {
#pragma unroll
        for (int r = 0; r < 4; ++r) {
          int row = mt * 16 + quad * 4 + r;
          float v = acc[r] + bsc;
          if constexpr (MODE == 2) {
            racc[(mt * 8 + nt) * 4 + r] += v;
          } else {
            if constexpr (MODE == 1) v += b2f(Res[row * ldr + n]);
            v = fmaxf(v, 0.f);
            Dst[row * ldd + n] = f2b(v);
          }
        }
      }
    }
  }
  __syncthreads();
}

// ---- view kernel: sample + PE + 8-layer view MLP -> r fragments (f32) ------
// 16384 blocks (bv*2048+g) x 64 threads; 32 points each. No racc.
__global__ __launch_bounds__(64, 3) void mvct_view(
    const float* __restrict__ angles, const int* __restrict__ idx,
    const unsigned short* __restrict__ wbuf,
    const float* __restrict__ vb_in, const float* __restrict__ vb1,
    const float* __restrict__ vb2, const float* __restrict__ vb_out)
{
  __shared__ __align__(16) unsigned short X[32][168];
  __shared__ __align__(16) unsigned short Hb[32][136];
  const int lane = threadIdx.x;
  const int bv = blockIdx.x >> 11;
  const int g = blockIdx.x & 2047;
  const int pts0 = g * 32;

  const unsigned short* w_in_t   = wbuf;
  const unsigned short* vw1_t    = wbuf + 20480;
  const unsigned short* vw2_t    = wbuf + 69632;
  const unsigned short* vw_out_t = wbuf + 118784;

  const float inv = 2.0f / 127.0f;
  const int pl = lane >> 4, cg = lane & 15;

  // PE into X cols 128..159
  if (lane < 32) {
    int id = idx[pts0 + lane];
    int iz = (id >> 14) & 127, iy = (id >> 7) & 127, ix = id & 127;
    float x = ix * inv - 1.f, y = iy * inv - 1.f, z = iz * inv - 1.f;
    const float PI = 3.14159265358979323846f;
    float pe[9] = {z, y, x, sinf(PI * z), sinf(PI * y), sinf(PI * x),
                   cosf(PI * z), cosf(PI * y), cosf(PI * x)};
#pragma unroll
    for (int j = 0; j < 9; ++j) X[lane][128 + j] = f2b(pe[j]);
    for (int j = 137; j < 160; ++j) X[lane][j] = 0;
  }
  __syncthreads();

  const float ang = angles[bv];
  const float ct = cosf(ang), st = sinf(ang);

  // bilinear gather of feats: 32 pts (4 pts/iter, 8 ch/lane)
  for (int it = 0; it < 8; ++it) {
    int lp = it * 4 + pl;
    int id = idx[pts0 + lp];
    int iz = (id >> 14) & 127, iy = (id >> 7) & 127, ix = id & 127;
    float x = ix * inv - 1.f, y = iy * inv - 1.f, z = iz * inv - 1.f;
    float u = x * ct - y * st;
    float px = (u + 1.f) * 127.5f, py = (z + 1.f) * 127.5f;
    px = fminf(fmaxf(px, 0.f), 255.f);
    py = fminf(fmaxf(py, 0.f), 255.f);
    int x0 = min((int)px, 254), y0 = min((int)py, 254);
    float wx = px - (float)x0, wy = py - (float)y0;
    const unsigned short* bp =
        g_feats + ((size_t)((bv * HH + y0) * WW + x0)) * CCH + cg * 8;
    ushort8 q00 = *(const ushort8*)bp;
    ushort8 q01 = *(const ushort8*)(bp + CCH);
    ushort8 q10 = *(const ushort8*)(bp + WW * CCH);
    ushort8 q11 = *(const ushort8*)(bp + WW * CCH + CCH);
    float w00 = (1.f - wx) * (1.f - wy), w01 = wx * (1.f - wy);
    float w10 = (1.f - wx) * wy, w11 = wx * wy;
    ushort8 o;
#pragma unroll
    for (int j = 0; j < 8; ++j) {
      float f = w00 * b2f(q00[j]) + w01 * b2f(q01[j]) +
                w10 * b2f(q10[j]) + w11 * b2f(q11[j]);
      o[j] = f2b(f);
    }
    *(ushort8*)&X[lp][cg * 8] = o;
  }
  __syncthreads();

  mlp_layer<160, 0>(&X[0][0], 168, w_in_t, vb_in,
                    nullptr, 0, &Hb[0][0], 136, nullptr, nullptr, lane);
#pragma unroll 1
  for (int i = 0; i < 3; ++i) {
    mlp_layer<128, 0>(&Hb[0][0], 136, vw1_t + i * 16384, vb1 + i * 128,
                      nullptr, 0, &X[0][0], 168, nullptr, nullptr, lane);
    mlp_layer<128, 1>(&X[0][0], 168, vw2_t + i * 16384, vb2 + i * 128,
                      &Hb[0][0], 136, &Hb[0][0], 136, nullptr, nullptr, lane);
  }
  floatx4* gout = g_rbuf + (size_t)blockIdx.x * 1024;  // 16 frags x 64 lanes
  mlp_layer<128, 3>(&Hb[0][0], 136, vw_out_t, vb_out,
                    nullptr, 0, nullptr, 0, nullptr, gout, lane);
}

// ---- global kernel: mean over 4 views + 5-layer global MLP + out -----------
// 4096 blocks (b*2048+g) x 64 threads; 32 points each.
__global__ __launch_bounds__(64) void mvct_global(
    const int* __restrict__ idx, const unsigned short* __restrict__ wbuf,
    const float* __restrict__ gb_in, const float* __restrict__ gb1,
    const float* __restrict__ gb2, const float* __restrict__ gw_out,
    const float* __restrict__ gb_out, float* __restrict__ out)
{
  __shared__ __align__(16) unsigned short X[32][168];
  __shared__ __align__(16) unsigned short Hb[32][136];
  const int lane = threadIdx.x;
  const int b = blockIdx.x >> 11;
  const int g = blockIdx.x & 2047;
  const int pts0 = g * 32;

  const unsigned short* gw_in_t = wbuf + 135168;
  const unsigned short* gw1_t   = wbuf + 151552;
  const unsigned short* gw2_t   = wbuf + 184320;

  // mean of r over views: fragment layout, f32
  floatx4 racc[16];
#pragma unroll
  for (int f = 0; f < 16; ++f) racc[f] = (floatx4){0.f, 0.f, 0.f, 0.f};
#pragma unroll
  for (int v = 0; v < VV; ++v) {
    const floatx4* rp = g_rbuf + ((size_t)((b * VV + v) * 2048 + g)) * 1024;
#pragma unroll
    for (int f = 0; f < 16; ++f) {
      floatx4 q = rp[f * 64 + lane];
      racc[f][0] += q[0]; racc[f][1] += q[1];
      racc[f][2] += q[2]; racc[f][3] += q[3];
    }
  }
  // scatter mean into X cols 0..127 (bf16); also init PE columns pad unused
  {
    const int col = lane & 15, quad = lane >> 4;
#pragma unroll
    for (int mt = 0; mt < 2; ++mt)
#pragma unroll
      for (int nt = 0; nt < 8; ++nt)
#pragma unroll
        for (int r = 0; r < 4; ++r)
          X[mt * 16 + quad * 4 + r][nt * 16 + col] =
              f2b(racc[mt * 8 + nt][r] * 0.25f);
  }
  __syncthreads();

  mlp_layer<128, 0>(&X[0][0], 168, gw_in_t, gb_in,
                    nullptr, 0, &Hb[0][0], 136, nullptr, nullptr, lane);
#pragma unroll 1
  for (int i = 0; i < 2; ++i) {
    mlp_layer<128, 0>(&Hb[0][0], 136, gw1_t + i * 16384, gb1 + i * 128,
                      nullptr, 0, &X[0][0], 168, nullptr, nullptr, lane);
    mlp_layer<128, 1>(&X[0][0], 168, gw2_t + i * 16384, gb2 + i * 128,
                      &Hb[0][0], 136, &Hb[0][0], 136, nullptr, nullptr, lane);
  }

  const int p = lane & 31, half = lane >> 5;
  float s = 0.f;
  const unsigned short* hr = &Hb[p][half * 64];
  const float* wo = gw_out + half * 64;
#pragma unroll
  for (int c = 0; c < 64; ++c)
    s += b2f(hr[c]) * wo[c];
  s += __shfl_xor(s, 32, 64);
  if (half == 0)
    out[(size_t)b * NPTSC + pts0 + p] = s + gb_out[0];
}

extern "C" void kernel_launch(void* const* d_in, const int* in_sizes, int n_in,
                              void* d_out, int out_size, void* d_ws, size_t ws_size,
                              hipStream_t stream) {
  const float* views  = (const float*)d_in[0];
  const float* angles = (const float*)d_in[1];
  const int*   idx    = (const int*)d_in[2];
  const float* conv_w = (const float*)d_in[3];
  const float* conv_b = (const float*)d_in[4];
  const float* vw_in  = (const float*)d_in[5];
  const float* vb_in  = (const float*)d_in[6];
  const float* vw1    = (const float*)d_in[7];
  const float* vb1    = (const float*)d_in[8];
  const float* vw2    = (const float*)d_in[9];
  const float* vb2    = (const float*)d_in[10];
  const float* vw_out = (const float*)d_in[11];
  const float* vb_out = (const float*)d_in[12];
  const float* gw_in  = (const float*)d_in[13];
  const float* gb_in  = (const float*)d_in[14];
  const float* gw1    = (const float*)d_in[15];
  const float* gb1    = (const float*)d_in[16];
  const float* gw2    = (const float*)d_in[17];
  const float* gb2    = (const float*)d_in[18];
  const float* gw_out = (const float*)d_in[19];
  const float* gb_out = (const float*)d_in[20];

  unsigned short* wbuf = (unsigned short*)d_ws;  // 434 KB

  hipLaunchKernelGGL(mvct_prep, dim3(848), dim3(256), 0, stream,
                     vw_in, vw1, vw2, vw_out, gw_in, gw1, gw2, wbuf);
  hipLaunchKernelGGL(mvct_conv, dim3(BB * VV * HH), dim3(128), 0, stream,
                     views, conv_w, conv_b);
  hipLaunchKernelGGL(mvct_view, dim3(BB * VV * 2048), dim3(64), 0, stream,
                     angles, idx, wbuf, vb_in, vb1, vb2, vb_out);
  hipLaunchKernelGGL(mvct_global, dim3(BB * 2048), dim3(64), 0, stream,
                     idx, wbuf, gb_in, gb1, gb2, gw_out, gb_out,
                     (float*)d_out);
}

// Round 20
// 759.369 us; speedup vs baseline: 1.1868x; 1.1868x over previous
//
#include <hip/hip_runtime.h>
#include <math.h>

#define BB 2
#define VV 4
#define NPTSC 65536
#define HH 256
#define WW 256
#define CCH 128

typedef __attribute__((ext_vector_type(8))) unsigned short ushort8;
typedef __attribute__((ext_vector_type(4))) unsigned short u16x4;
typedef __attribute__((ext_vector_type(8))) __bf16 bf16x8;
typedef __attribute__((ext_vector_type(4))) float floatx4;

// Static feats buffer (128 MiB); rewritten fully every launch.
__device__ unsigned short g_feats[(size_t)BB * VV * HH * WW * CCH];

__device__ __forceinline__ float b2f(unsigned short u) {
  unsigned int x = ((unsigned int)u) << 16;
  return __builtin_bit_cast(float, x);
}
__device__ __forceinline__ unsigned short f2b(float f) {
  unsigned int x = __builtin_bit_cast(unsigned int, f);
  x = x + 0x7fffu + ((x >> 16) & 1u);
  return (unsigned short)(x >> 16);
}

// ---- prep: f32 weights -> bf16 [out][in] into d_ws (434 KB) ----------------
__global__ __launch_bounds__(256) void mvct_prep(
    const float* __restrict__ vw_in, const float* __restrict__ vw1,
    const float* __restrict__ vw2, const float* __restrict__ vw_out,
    const float* __restrict__ gw_in, const float* __restrict__ gw1,
    const float* __restrict__ gw2, unsigned short* __restrict__ wbuf)
{
  int tid = blockIdx.x * 256 + threadIdx.x;
  if (tid >= 217088) return;
  float val;
  if (tid < 20480) {
    int n = tid / 160, k = tid - n * 160;
    val = (k < 137) ? vw_in[k * 128 + n] : 0.f;
  } else {
    int t = tid - 20480;
    const float* src;
    if (t < 49152) { src = vw1; }
    else if (t < 98304) { t -= 49152; src = vw2; }
    else if (t < 114688) { t -= 98304; src = vw_out; }
    else if (t < 131072) { t -= 114688; src = gw_in; }
    else if (t < 163840) { t -= 131072; src = gw1; }
    else { t -= 163840; src = gw2; }
    int i = t >> 14; int r = t & 16383; int n = r >> 7; int k = r & 127;
    val = src[i * 16384 + k * 128 + n];
  }
  wbuf[tid] = f2b(val);
}

// ---- conv 3x3 SAME, 1->128 ch, relu, channel-last bf16 into g_feats --------
__global__ __launch_bounds__(128) void mvct_conv(
    const float* __restrict__ views, const float* __restrict__ conv_w,
    const float* __restrict__ conv_b)
{
  int bv = blockIdx.x >> 8;
  int y = blockIdx.x & 255;
  int c = threadIdx.x;
  float w[9];
#pragma unroll
  for (int j = 0; j < 9; ++j) w[j] = conv_w[c * 9 + j];
  float bias = conv_b[c];

  __shared__ float rows[3][258];
  const float* img = views + (size_t)bv * HH * WW;
#pragma unroll
  for (int r = 0; r < 3; ++r) {
    int yy = y - 1 + r;
    for (int x = c; x < 258; x += 128) {
      int xx = x - 1;
      float v = 0.f;
      if (yy >= 0 && yy < HH && xx >= 0 && xx < WW) v = img[yy * WW + xx];
      rows[r][x] = v;
    }
  }
  __syncthreads();

  unsigned short* orow = g_feats + ((size_t)(bv * HH + y) * WW) * CCH + c;
  for (int x = 0; x < WW; ++x) {
    float acc = bias;
#pragma unroll
    for (int r = 0; r < 3; ++r)
#pragma unroll
      for (int d = 0; d < 3; ++d)
        acc += rows[r][x + d] * w[r * 3 + d];
    acc = fmaxf(acc, 0.f);
    orow[(size_t)x * CCH] = f2b(acc);
  }
}

// ---- MFMA MLP layer, operand-swapped: A=weights (m=out-feat), B=acts (n=pt) -
// D[m=ft*16+quad*4+r][n=pt*16+col] -> lane holds 4 CONSECUTIVE features of one
// point => b64 epilogue. 2 waves/block split the 8 ftiles (ftBase = wave*4).
// Act: LDS [32][lda] bf16 rows=points. Wt: [128][K] bf16 row=out-feature.
// MODE 0: relu+store; MODE 1: relu+residual+store; MODE 2: accumulate to racc.
template<int K, int MODE>
__device__ __forceinline__ void mlp_layer(
    const unsigned short* Act, int lda,
    const unsigned short* __restrict__ Wt,
    const float* __restrict__ bias,
    const unsigned short* Res, int ldr,
    unsigned short* Dst, int ldd,
    float* racc, int lane, int ftBase)
{
  constexpr int NK = K / 32;
  const int col = lane & 15, quad = lane >> 4;
  ushort8 bfr[2][NK];
#pragma unroll
  for (int pt = 0; pt < 2; ++pt)
#pragma unroll
    for (int kk = 0; kk < NK; ++kk)
      bfr[pt][kk] = *(const ushort8*)(Act + (pt * 16 + col) * lda + kk * 32 + quad * 8);
#pragma unroll
  for (int ftl = 0; ftl < 4; ++ftl) {
    const int ft = ftBase + ftl;
    ushort8 afr[NK];
#pragma unroll
    for (int kk = 0; kk < NK; ++kk)
      afr[kk] = *(const ushort8*)(Wt + (ft * 16 + col) * K + kk * 32 + quad * 8);
    floatx4 bs4 = *(const floatx4*)(bias + ft * 16 + quad * 4);
#pragma unroll
    for (int pt = 0; pt < 2; ++pt) {
      floatx4 acc = {0.f, 0.f, 0.f, 0.f};
#pragma unroll
      for (int kk = 0; kk < NK; ++kk)
        acc = __builtin_amdgcn_mfma_f32_16x16x32_bf16(
            __builtin_bit_cast(bf16x8, afr[kk]),
            __builtin_bit_cast(bf16x8, bfr[pt][kk]), acc, 0, 0, 0);
      const int point = pt * 16 + col;
      if constexpr (MODE == 2) {
#pragma unroll
        for (int r = 0; r < 4; ++r)
          racc[(ftl * 2 + pt) * 4 + r] += acc[r] + bs4[r];
      } else {
        u16x4 rv;
        if constexpr (MODE == 1)
          rv = *(const u16x4*)(Res + point * ldr + ft * 16 + quad * 4);
        u16x4 o;
#pragma unroll
        for (int r = 0; r < 4; ++r) {
          float v = acc[r] + bs4[r];
          if constexpr (MODE == 1) v += b2f(rv[r]);
          v = fmaxf(v, 0.f);
          o[r] = f2b(v);
        }
        *(u16x4*)(Dst + point * ldd + ft * 16 + quad * 4) = o;
      }
    }
  }
  __syncthreads();
}

// ---- main: sample + PE + view MLP x4 + mean + global MLP -------------------
// 4096 blocks x 128 thr (2 waves, ftile-split). 32 points/block. LDS 19.5 KB.
__global__ __launch_bounds__(128) void mvct_main(
    const float* __restrict__ angles, const int* __restrict__ idx,
    const unsigned short* __restrict__ wbuf,
    const float* __restrict__ vb_in, const float* __restrict__ vb1,
    const float* __restrict__ vb2, const float* __restrict__ vb_out,
    const float* __restrict__ gb_in, const float* __restrict__ gb1,
    const float* __restrict__ gb2, const float* __restrict__ gw_out,
    const float* __restrict__ gb_out,
    float* __restrict__ out)
{
  __shared__ __align__(16) unsigned short X[32][168];  // xin(160)/t(128)
  __shared__ __align__(16) unsigned short Hb[32][136]; // h
  const int tid = threadIdx.x;
  const int lane = tid & 63;
  const int ftBase = (tid >> 6) * 4;  // wave 0: ft 0-3, wave 1: ft 4-7
  const int b = blockIdx.x >> 11;                 // FIXED: 2048 groups/batch
  const int pts0 = (blockIdx.x & 2047) * 32;      // FIXED

  const unsigned short* w_in_t   = wbuf;
  const unsigned short* vw1_t    = wbuf + 20480;
  const unsigned short* vw2_t    = wbuf + 69632;
  const unsigned short* vw_out_t = wbuf + 118784;
  const unsigned short* gw_in_t  = wbuf + 135168;
  const unsigned short* gw1_t    = wbuf + 151552;
  const unsigned short* gw2_t    = wbuf + 184320;

  const float inv = 2.0f / 127.0f;
  const int col = lane & 15, quad = lane >> 4;

  // PE into X cols 128..159 (never clobbered: layer stores touch cols<128)
  if (tid < 32) {
    int id = idx[pts0 + tid];
    int iz = (id >> 14) & 127, iy = (id >> 7) & 127, ix = id & 127;
    float x = ix * inv - 1.f, y = iy * inv - 1.f, z = iz * inv - 1.f;
    const float PI = 3.14159265358979323846f;
    float pe[9] = {z, y, x, sinf(PI * z), sinf(PI * y), sinf(PI * x),
                   cosf(PI * z), cosf(PI * y), cosf(PI * x)};
#pragma unroll
    for (int j = 0; j < 9; ++j) X[tid][128 + j] = f2b(pe[j]);
    for (int j = 137; j < 160; ++j) X[tid][j] = 0;
  }
  __syncthreads();

  float racc[32];
#pragma unroll
  for (int i = 0; i < 32; ++i) racc[i] = 0.f;

#pragma unroll 1
  for (int v = 0; v < VV; ++v) {
    const int bv = b * VV + v;
    const float ang = angles[bv];
    const float ct = cosf(ang), st = sinf(ang);

    // bilinear gather: 128 threads, 8 pts/iter (tid>>4), 8 ch/lane (tid&15)
    const int pg = tid >> 4, cg = tid & 15;
    for (int it = 0; it < 4; ++it) {
      int lp = it * 8 + pg;
      int id = idx[pts0 + lp];
      int iz = (id >> 14) & 127, iy = (id >> 7) & 127, ix = id & 127;
      float x = ix * inv - 1.f, y = iy * inv - 1.f, z = iz * inv - 1.f;
      float u = x * ct - y * st;
      float px = (u + 1.f) * 127.5f, py = (z + 1.f) * 127.5f;
      px = fminf(fmaxf(px, 0.f), 255.f);
      py = fminf(fmaxf(py, 0.f), 255.f);
      int x0 = min((int)px, 254), y0 = min((int)py, 254);
      float wx = px - (float)x0, wy = py - (float)y0;
      const unsigned short* bp =
          g_feats + ((size_t)((bv * HH + y0) * WW + x0)) * CCH + cg * 8;
      ushort8 q00 = *(const ushort8*)bp;
      ushort8 q01 = *(const ushort8*)(bp + CCH);
      ushort8 q10 = *(const ushort8*)(bp + WW * CCH);
      ushort8 q11 = *(const ushort8*)(bp + WW * CCH + CCH);
      float w00 = (1.f - wx) * (1.f - wy), w01 = wx * (1.f - wy);
      float w10 = (1.f - wx) * wy, w11 = wx * wy;
      ushort8 o;
#pragma unroll
      for (int j = 0; j < 8; ++j) {
        float f = w00 * b2f(q00[j]) + w01 * b2f(q01[j]) +
                  w10 * b2f(q10[j]) + w11 * b2f(q11[j]);
        o[j] = f2b(f);
      }
      *(ushort8*)&X[lp][cg * 8] = o;
    }
    __syncthreads();

    mlp_layer<160, 0>(&X[0][0], 168, w_in_t, vb_in,
                      nullptr, 0, &Hb[0][0], 136, nullptr, lane, ftBase);
#pragma unroll 1
    for (int i = 0; i < 3; ++i) {
      mlp_layer<128, 0>(&Hb[0][0], 136, vw1_t + i * 16384, vb1 + i * 128,
                        nullptr, 0, &X[0][0], 168, nullptr, lane, ftBase);
      mlp_layer<128, 1>(&X[0][0], 168, vw2_t + i * 16384, vb2 + i * 128,
                        &Hb[0][0], 136, &Hb[0][0], 136, nullptr, lane, ftBase);
    }
    mlp_layer<128, 2>(&Hb[0][0], 136, vw_out_t, vb_out,
                      nullptr, 0, nullptr, 0, racc, lane, ftBase);
  }

  // mean over views -> X cols 0..127 (bf16), b64 stores
#pragma unroll
  for (int ftl = 0; ftl < 4; ++ftl)
#pragma unroll
    for (int pt = 0; pt < 2; ++pt) {
      const int point = pt * 16 + col;
      u16x4 o;
#pragma unroll
      for (int r = 0; r < 4; ++r)
        o[r] = f2b(racc[(ftl * 2 + pt) * 4 + r] * 0.25f);
      *(u16x4*)(&X[point][(ftBase + ftl) * 16 + quad * 4]) = o;
    }
  __syncthreads();

  mlp_layer<128, 0>(&X[0][0], 168, gw_in_t, gb_in,
                    nullptr, 0, &Hb[0][0], 136, nullptr, lane, ftBase);
#pragma unroll 1
  for (int i = 0; i < 2; ++i) {
    mlp_layer<128, 0>(&Hb[0][0], 136, gw1_t + i * 16384, gb1 + i * 128,
                      nullptr, 0, &X[0][0], 168, nullptr, lane, ftBase);
    mlp_layer<128, 1>(&X[0][0], 168, gw2_t + i * 16384, gb2 + i * 128,
                      &Hb[0][0], 136, &Hb[0][0], 136, nullptr, lane, ftBase);
  }

  // out = h @ gw_out + gb_out; wave 0 only, 2 lanes per point; f32 output
  if (tid < 64) {
    const int p = tid & 31, half = tid >> 5;
    float s = 0.f;
    const unsigned short* hr = &Hb[p][half * 64];
    const float* wo = gw_out + half * 64;
#pragma unroll
    for (int c = 0; c < 64; ++c)
      s += b2f(hr[c]) * wo[c];
    s += __shfl_xor(s, 32, 64);
    if (half == 0)
      out[(size_t)b * NPTSC + pts0 + p] = s + gb_out[0];
  }
}

extern "C" void kernel_launch(void* const* d_in, const int* in_sizes, int n_in,
                              void* d_out, int out_size, void* d_ws, size_t ws_size,
                              hipStream_t stream) {
  const float* views  = (const float*)d_in[0];
  const float* angles = (const float*)d_in[1];
  const int*   idx    = (const int*)d_in[2];
  const float* conv_w = (const float*)d_in[3];
  const float* conv_b = (const float*)d_in[4];
  const float* vw_in  = (const float*)d_in[5];
  const float* vb_in  = (const float*)d_in[6];
  const float* vw1    = (const float*)d_in[7];
  const float* vb1    = (const float*)d_in[8];
  const float* vw2    = (const float*)d_in[9];
  const float* vb2    = (const float*)d_in[10];
  const float* vw_out = (const float*)d_in[11];
  const float* vb_out = (const float*)d_in[12];
  const float* gw_in  = (const float*)d_in[13];
  const float* gb_in  = (const float*)d_in[14];
  const float* gw1    = (const float*)d_in[15];
  const float* gb1    = (const float*)d_in[16];
  const float* gw2    = (const float*)d_in[17];
  const float* gb2    = (const float*)d_in[18];
  const float* gw_out = (const float*)d_in[19];
  const float* gb_out = (const float*)d_in[20];

  unsigned short* wbuf = (unsigned short*)d_ws;  // 434 KB

  hipLaunchKernelGGL(mvct_prep, dim3(848), dim3(256), 0, stream,
                     vw_in, vw1, vw2, vw_out, gw_in, gw1, gw2, wbuf);
  hipLaunchKernelGGL(mvct_conv, dim3(BB * VV * HH), dim3(128), 0, stream,
                     views, conv_w, conv_b);
  hipLaunchKernelGGL(mvct_main, dim3(BB * (NPTSC / 32)), dim3(128), 0, stream,
                     angles, idx, wbuf, vb_in, vb1, vb2, vb_out,
                     gb_in, gb1, gb2, gw_out, gb_out,
                     (float*)d_out);
}

// Round 21
// 550.725 us; speedup vs baseline: 1.6364x; 1.3789x over previous
//
#include <hip/hip_runtime.h>
#include <math.h>

#define BB 2
#define VV 4
#define NPTSC 65536
#define HH 256
#define WW 256
#define CCH 128

typedef __attribute__((ext_vector_type(8))) unsigned short ushort8;
typedef __attribute__((ext_vector_type(4))) unsigned short u16x4;
typedef __attribute__((ext_vector_type(8))) __bf16 bf16x8;
typedef __attribute__((ext_vector_type(4))) float floatx4;

// Static feats buffer (128 MiB); rewritten fully every launch.
__device__ unsigned short g_feats[(size_t)BB * VV * HH * WW * CCH];

__device__ __forceinline__ float b2f(unsigned short u) {
  unsigned int x = ((unsigned int)u) << 16;
  return __builtin_bit_cast(float, x);
}
__device__ __forceinline__ unsigned short f2b(float f) {
  unsigned int x = __builtin_bit_cast(unsigned int, f);
  x = x + 0x7fffu + ((x >> 16) & 1u);
  return (unsigned short)(x >> 16);
}

// ---- prep: f32 weights -> bf16 [out][in] into d_ws (434 KB) ----------------
__global__ __launch_bounds__(256) void mvct_prep(
    const float* __restrict__ vw_in, const float* __restrict__ vw1,
    const float* __restrict__ vw2, const float* __restrict__ vw_out,
    const float* __restrict__ gw_in, const float* __restrict__ gw1,
    const float* __restrict__ gw2, unsigned short* __restrict__ wbuf)
{
  int tid = blockIdx.x * 256 + threadIdx.x;
  if (tid >= 217088) return;
  float val;
  if (tid < 20480) {
    int n = tid / 160, k = tid - n * 160;
    val = (k < 137) ? vw_in[k * 128 + n] : 0.f;
  } else {
    int t = tid - 20480;
    const float* src;
    if (t < 49152) { src = vw1; }
    else if (t < 98304) { t -= 49152; src = vw2; }
    else if (t < 114688) { t -= 98304; src = vw_out; }
    else if (t < 131072) { t -= 114688; src = gw_in; }
    else if (t < 163840) { t -= 131072; src = gw1; }
    else { t -= 163840; src = gw2; }
    int i = t >> 14; int r = t & 16383; int n = r >> 7; int k = r & 127;
    val = src[i * 16384 + k * 128 + n];
  }
  wbuf[tid] = f2b(val);
}

// ---- conv 3x3 SAME, 1->128 ch, relu, channel-last bf16 into g_feats --------
__global__ __launch_bounds__(128) void mvct_conv(
    const float* __restrict__ views, const float* __restrict__ conv_w,
    const float* __restrict__ conv_b)
{
  int bv = blockIdx.x >> 8;
  int y = blockIdx.x & 255;
  int c = threadIdx.x;
  float w[9];
#pragma unroll
  for (int j = 0; j < 9; ++j) w[j] = conv_w[c * 9 + j];
  float bias = conv_b[c];

  __shared__ float rows[3][258];
  const float* img = views + (size_t)bv * HH * WW;
#pragma unroll
  for (int r = 0; r < 3; ++r) {
    int yy = y - 1 + r;
    for (int x = c; x < 258; x += 128) {
      int xx = x - 1;
      float v = 0.f;
      if (yy >= 0 && yy < HH && xx >= 0 && xx < WW) v = img[yy * WW + xx];
      rows[r][x] = v;
    }
  }
  __syncthreads();

  unsigned short* orow = g_feats + ((size_t)(bv * HH + y) * WW) * CCH + c;
  for (int x = 0; x < WW; ++x) {
    float acc = bias;
#pragma unroll
    for (int r = 0; r < 3; ++r)
#pragma unroll
      for (int d = 0; d < 3; ++d)
        acc += rows[r][x + d] * w[r * 3 + d];
    acc = fmaxf(acc, 0.f);
    orow[(size_t)x * CCH] = f2b(acc);
  }
}

// ---- MFMA MLP layer, operand-swapped, multi-pt-tile ------------------------
// A=weights (m=out-feature), B=acts (n=batch row). NPT = # of 16-row tiles.
// Each wave owns 2 ftiles (ftBase = waveId*2); weights hoisted in registers,
// activations streamed per pt-tile. D[m=ft*16+quad*4+r][n=ptt*16+col].
// MODE 0: relu+store; MODE 1: relu+residual+store; MODE 2: accumulate racc
// (racc[ftl*4+r] summed over ALL pt-tiles => mean over views when ptt==view).
template<int K, int MODE, int NPT>
__device__ __forceinline__ void mlp_layer(
    const unsigned short* Act, int lda,
    const unsigned short* __restrict__ Wt,
    const float* __restrict__ bias,
    const unsigned short* Res, int ldr,
    unsigned short* Dst, int ldd,
    float* racc, int lane, int ftBase)
{
  constexpr int NK = K / 32;
  const int col = lane & 15, quad = lane >> 4;
  ushort8 afr[2][NK];
  floatx4 bs4[2];
#pragma unroll
  for (int ftl = 0; ftl < 2; ++ftl) {
    const int ft = ftBase + ftl;
#pragma unroll
    for (int kk = 0; kk < NK; ++kk)
      afr[ftl][kk] = *(const ushort8*)(Wt + (ft * 16 + col) * K + kk * 32 + quad * 8);
    bs4[ftl] = *(const floatx4*)(bias + ft * 16 + quad * 4);
  }
#pragma unroll
  for (int ptt = 0; ptt < NPT; ++ptt) {
    ushort8 bfr[NK];
#pragma unroll
    for (int kk = 0; kk < NK; ++kk)
      bfr[kk] = *(const ushort8*)(Act + (ptt * 16 + col) * lda + kk * 32 + quad * 8);
#pragma unroll
    for (int ftl = 0; ftl < 2; ++ftl) {
      const int ft = ftBase + ftl;
      floatx4 acc = {0.f, 0.f, 0.f, 0.f};
#pragma unroll
      for (int kk = 0; kk < NK; ++kk)
        acc = __builtin_amdgcn_mfma_f32_16x16x32_bf16(
            __builtin_bit_cast(bf16x8, afr[ftl][kk]),
            __builtin_bit_cast(bf16x8, bfr[kk]), acc, 0, 0, 0);
      const int row = ptt * 16 + col;
      if constexpr (MODE == 2) {
#pragma unroll
        for (int r = 0; r < 4; ++r)
          racc[ftl * 4 + r] += acc[r] + bs4[ftl][r];
      } else {
        u16x4 rv;
        if constexpr (MODE == 1)
          rv = *(const u16x4*)(Res + row * ldr + ft * 16 + quad * 4);
        u16x4 o;
#pragma unroll
        for (int r = 0; r < 4; ++r) {
          float v = acc[r] + bs4[ftl][r];
          if constexpr (MODE == 1) v += b2f(rv[r]);
          v = fmaxf(v, 0.f);
          o[r] = f2b(v);
        }
        *(u16x4*)(Dst + row * ldd + ft * 16 + quad * 4) = o;
      }
    }
  }
  __syncthreads();
}

// ---- main: 4-view-batched. 8192 blocks x 256 thr (4 waves), 16 pts/block ---
// Rows = (view, point): row = v*16+p, 64 rows. View MLP: 8 layer-calls on 64
// rows. Mean falls out of MODE2 (pt-tile == view). Global MLP on 16 rows.
// LDS: X[64][168] + Hb[64][136] = 38.9 KB.
__global__ __launch_bounds__(256, 3) void mvct_main(
    const float* __restrict__ angles, const int* __restrict__ idx,
    const unsigned short* __restrict__ wbuf,
    const float* __restrict__ vb_in, const float* __restrict__ vb1,
    const float* __restrict__ vb2, const float* __restrict__ vb_out,
    const float* __restrict__ gb_in, const float* __restrict__ gb1,
    const float* __restrict__ gb2, const float* __restrict__ gw_out,
    const float* __restrict__ gb_out,
    float* __restrict__ out)
{
  __shared__ __align__(16) unsigned short X[64][168];
  __shared__ __align__(16) unsigned short Hb[64][136];
  const int tid = threadIdx.x;
  const int lane = tid & 63;
  const int ftBase = (tid >> 6) * 2;           // wave w: ftiles 2w, 2w+1
  const int b = blockIdx.x >> 12;              // 4096 groups per batch
  const int pts0 = (blockIdx.x & 4095) * 16;

  const unsigned short* w_in_t   = wbuf;
  const unsigned short* vw1_t    = wbuf + 20480;
  const unsigned short* vw2_t    = wbuf + 69632;
  const unsigned short* vw_out_t = wbuf + 118784;
  const unsigned short* gw_in_t  = wbuf + 135168;
  const unsigned short* gw1_t    = wbuf + 151552;
  const unsigned short* gw2_t    = wbuf + 184320;

  const float inv = 2.0f / 127.0f;
  const int col = lane & 15, quad = lane >> 4;

  // PE into X rows 0..63 cols 128..159 (per-row point p = row&15)
  if (tid < 64) {
    int p = tid & 15;
    int id = idx[pts0 + p];
    int iz = (id >> 14) & 127, iy = (id >> 7) & 127, ix = id & 127;
    float x = ix * inv - 1.f, y = iy * inv - 1.f, z = iz * inv - 1.f;
    const float PI = 3.14159265358979323846f;
    float pe[9] = {z, y, x, sinf(PI * z), sinf(PI * y), sinf(PI * x),
                   cosf(PI * z), cosf(PI * y), cosf(PI * x)};
#pragma unroll
    for (int j = 0; j < 9; ++j) X[tid][128 + j] = f2b(pe[j]);
    for (int j = 137; j < 160; ++j) X[tid][j] = 0;
  }

  // sampling: 4 iters; iter v: thread -> (p = tid>>4 & 15, cg = tid&15)
  for (int v = 0; v < VV; ++v) {
    const int bv = b * VV + v;
    const float ang = angles[bv];
    const float ct = cosf(ang), st = sinf(ang);
    const int p = (tid >> 4) & 15, cg = tid & 15;
    int id = idx[pts0 + p];
    int iz = (id >> 14) & 127, iy = (id >> 7) & 127, ix = id & 127;
    float x = ix * inv - 1.f, y = iy * inv - 1.f, z = iz * inv - 1.f;
    float u = x * ct - y * st;
    float px = (u + 1.f) * 127.5f, py = (z + 1.f) * 127.5f;
    px = fminf(fmaxf(px, 0.f), 255.f);
    py = fminf(fmaxf(py, 0.f), 255.f);
    int x0 = min((int)px, 254), y0 = min((int)py, 254);
    float wx = px - (float)x0, wy = py - (float)y0;
    const unsigned short* bp =
        g_feats + ((size_t)((bv * HH + y0) * WW + x0)) * CCH + cg * 8;
    ushort8 q00 = *(const ushort8*)bp;
    ushort8 q01 = *(const ushort8*)(bp + CCH);
    ushort8 q10 = *(const ushort8*)(bp + WW * CCH);
    ushort8 q11 = *(const ushort8*)(bp + WW * CCH + CCH);
    float w00 = (1.f - wx) * (1.f - wy), w01 = wx * (1.f - wy);
    float w10 = (1.f - wx) * wy, w11 = wx * wy;
    ushort8 o;
#pragma unroll
    for (int j = 0; j < 8; ++j) {
      float f = w00 * b2f(q00[j]) + w01 * b2f(q01[j]) +
                w10 * b2f(q10[j]) + w11 * b2f(q11[j]);
      o[j] = f2b(f);
    }
    *(ushort8*)&X[v * 16 + p][cg * 8] = o;
  }
  __syncthreads();

  // view MLP, batched over 64 rows (4 pt-tiles = 4 views)
  float racc[8];
#pragma unroll
  for (int i = 0; i < 8; ++i) racc[i] = 0.f;

  mlp_layer<160, 0, 4>(&X[0][0], 168, w_in_t, vb_in,
                       nullptr, 0, &Hb[0][0], 136, nullptr, lane, ftBase);
#pragma unroll 1
  for (int i = 0; i < 3; ++i) {
    mlp_layer<128, 0, 4>(&Hb[0][0], 136, vw1_t + i * 16384, vb1 + i * 128,
                         nullptr, 0, &X[0][0], 168, nullptr, lane, ftBase);
    mlp_layer<128, 1, 4>(&X[0][0], 168, vw2_t + i * 16384, vb2 + i * 128,
                         &Hb[0][0], 136, &Hb[0][0], 136, nullptr, lane, ftBase);
  }
  mlp_layer<128, 2, 4>(&Hb[0][0], 136, vw_out_t, vb_out,
                       nullptr, 0, nullptr, 0, racc, lane, ftBase);

  // mean over views (racc summed the 4 pt-tiles) -> X rows 0..15 cols 0..127
#pragma unroll
  for (int ftl = 0; ftl < 2; ++ftl) {
    u16x4 o;
#pragma unroll
    for (int r = 0; r < 4; ++r)
      o[r] = f2b(racc[ftl * 4 + r] * 0.25f);
    *(u16x4*)(&X[col][(ftBase + ftl) * 16 + quad * 4]) = o;
  }
  __syncthreads();

  // global MLP on 16 rows (1 pt-tile)
  mlp_layer<128, 0, 1>(&X[0][0], 168, gw_in_t, gb_in,
                       nullptr, 0, &Hb[0][0], 136, nullptr, lane, ftBase);
#pragma unroll 1
  for (int i = 0; i < 2; ++i) {
    mlp_layer<128, 0, 1>(&Hb[0][0], 136, gw1_t + i * 16384, gb1 + i * 128,
                         nullptr, 0, &X[0][0], 168, nullptr, lane, ftBase);
    mlp_layer<128, 1, 1>(&X[0][0], 168, gw2_t + i * 16384, gb2 + i * 128,
                         &Hb[0][0], 136, &Hb[0][0], 136, nullptr, lane, ftBase);
  }

  // out = h @ gw_out + gb_out; 16 points, 4 lanes/point (wave 0)
  if (tid < 64) {
    const int p = tid & 15, q4 = tid >> 4;
    float s = 0.f;
    const unsigned short* hr = &Hb[p][q4 * 32];
    const float* wo = gw_out + q4 * 32;
#pragma unroll
    for (int c = 0; c < 32; ++c)
      s += b2f(hr[c]) * wo[c];
    s += __shfl_xor(s, 16, 64);
    s += __shfl_xor(s, 32, 64);
    if (q4 == 0)
      out[(size_t)b * NPTSC + pts0 + p] = s + gb_out[0];
  }
}

extern "C" void kernel_launch(void* const* d_in, const int* in_sizes, int n_in,
                              void* d_out, int out_size, void* d_ws, size_t ws_size,
                              hipStream_t stream) {
  const float* views  = (const float*)d_in[0];
  const float* angles = (const float*)d_in[1];
  const int*   idx    = (const int*)d_in[2];
  const float* conv_w = (const float*)d_in[3];
  const float* conv_b = (const float*)d_in[4];
  const float* vw_in  = (const float*)d_in[5];
  const float* vb_in  = (const float*)d_in[6];
  const float* vw1    = (const float*)d_in[7];
  const float* vb1    = (const float*)d_in[8];
  const float* vw2    = (const float*)d_in[9];
  const float* vb2    = (const float*)d_in[10];
  const float* vw_out = (const float*)d_in[11];
  const float* vb_out = (const float*)d_in[12];
  const float* gw_in  = (const float*)d_in[13];
  const float* gb_in  = (const float*)d_in[14];
  const float* gw1    = (const float*)d_in[15];
  const float* gb1    = (const float*)d_in[16];
  const float* gw2    = (const float*)d_in[17];
  const float* gb2    = (const float*)d_in[18];
  const float* gw_out = (const float*)d_in[19];
  const float* gb_out = (const float*)d_in[20];

  unsigned short* wbuf = (unsigned short*)d_ws;  // 434 KB

  hipLaunchKernelGGL(mvct_prep, dim3(848), dim3(256), 0, stream,
                     vw_in, vw1, vw2, vw_out, gw_in, gw1, gw2, wbuf);
  hipLaunchKernelGGL(mvct_conv, dim3(BB * VV * HH), dim3(128), 0, stream,
                     views, conv_w, conv_b);
  hipLaunchKernelGGL(mvct_main, dim3(BB * (NPTSC / 16)), dim3(256), 0, stream,
                     angles, idx, wbuf, vb_in, vb1, vb2, vb_out,
                     gb_in, gb1, gb2, gw_out, gb_out,
                     (float*)d_out);
}